// Round 1
// baseline (2203.107 us; speedup 1.0000x reference)
//
#include <hip/hip_runtime.h>

#define NN 20000
#define NE 320000
#define NH 4
#define NL 3
#define NP 8192
#define EDIM 9
#define HIDD 4096
#define TC 128
#define TROWS 64
#define MAXT 136
#define CAPR (MAXT*TROWS)

// k_resmm LDS strides (chosen for 16B-aligned float4 LDS reads)
#define ZRS 68
#define W1S 36
#define W2S 132
#define TSS 68

__device__ __forceinline__ unsigned ordf(float f){ unsigned u=__float_as_uint(f); return (u>>31)? ~u : (u|0x80000000u); }
__device__ __forceinline__ float unordf(unsigned u){ return (u>>31)? __uint_as_float(u&0x7fffffffu) : __uint_as_float(~u); }
__device__ __forceinline__ float sigm(float x){ return 1.f/(1.f+__expf(-x)); }

__global__ void k_fill_f(float* __restrict__ p, int n, float v){ int i=blockIdx.x*blockDim.x+threadIdx.x; if(i<n)p[i]=v; }
__global__ void k_fill_i(int* __restrict__ p, int n, int v){ int i=blockIdx.x*blockDim.x+threadIdx.x; if(i<n)p[i]=v; }

__global__ void k_leaky(float* __restrict__ h, int n){
  int i=blockIdx.x*blockDim.x+threadIdx.x;
  if(i<n){ float v=h[i]; h[i]=v>0.f?v:0.01f*v; }
}

__global__ void k_deg(const int* __restrict__ ei, int* __restrict__ deg){
  int e=blockIdx.x*blockDim.x+threadIdx.x; if(e<NE) atomicAdd(&deg[ei[NE+e]],1);
}

__global__ __launch_bounds__(1024) void k_scan(const int* __restrict__ deg, int* __restrict__ row_ptr, int* __restrict__ cursor){
  __shared__ int sh[1024];
  __shared__ int carry;
  int tid=threadIdx.x;
  if(tid==0) carry=0;
  __syncthreads();
  for(int base=0;base<NN;base+=1024){
    int i=base+tid;
    int v=(i<NN)?deg[i]:0;
    sh[tid]=v; __syncthreads();
    for(int o=1;o<1024;o<<=1){
      int t=(tid>=o)?sh[tid-o]:0; __syncthreads();
      sh[tid]+=t; __syncthreads();
    }
    int incl=sh[tid];
    int c=carry;
    if(i<NN){ row_ptr[i+1]=c+incl; cursor[i]=c+incl-v; }
    if(i==0) row_ptr[0]=0;
    __syncthreads();
    if(tid==1023) carry=c+incl;
    __syncthreads();
  }
}

__global__ void k_fill_csr(const int* __restrict__ ei, int* __restrict__ cursor, int* __restrict__ csr){
  int e=blockIdx.x*blockDim.x+threadIdx.x;
  if(e<NE){ int t=ei[NE+e]; int pos=atomicAdd(&cursor[t],1); csr[pos]=e; }
}

// xl = hin@Wl + bl ; xr = hin@Wr + br   (K=64, out 256 each)
__global__ __launch_bounds__(256) void k_nodexf(const float* __restrict__ hin,
    const float* __restrict__ Wl, const float* __restrict__ bl,
    const float* __restrict__ Wr, const float* __restrict__ br,
    float* __restrict__ xl, float* __restrict__ xr){
  __shared__ float hs[64][66];
  __shared__ float ws[64][66];
  int n0=blockIdx.x*64, tid=threadIdx.x;
  for(int idx=tid; idx<64*64; idx+=256){ int r=idx>>6,k=idx&63; int n=n0+r; hs[r][k]=(n<NN)?hin[(size_t)n*64+k]:0.f; }
  int ty=tid>>4, tx=tid&15;
  for(int ch=0; ch<8; ++ch){
    const float* W=(ch<4)?Wl:Wr;
    const float* bb=(ch<4)?bl:br;
    float* outp=(ch<4)?xl:xr;
    int c0=(ch&3)*64;
    __syncthreads();
    for(int idx=tid; idx<64*64; idx+=256){ int k=idx>>6,j=idx&63; ws[k][j]=W[(size_t)k*256+c0+j]; }
    __syncthreads();
    float acc[4][4]={};
    #pragma unroll 4
    for(int k=0;k<64;++k){
      float a0=hs[4*ty+0][k],a1=hs[4*ty+1][k],a2=hs[4*ty+2][k],a3=hs[4*ty+3][k];
      float b0=ws[k][4*tx+0],b1v=ws[k][4*tx+1],b2v=ws[k][4*tx+2],b3v=ws[k][4*tx+3];
      acc[0][0]+=a0*b0; acc[0][1]+=a0*b1v; acc[0][2]+=a0*b2v; acc[0][3]+=a0*b3v;
      acc[1][0]+=a1*b0; acc[1][1]+=a1*b1v; acc[1][2]+=a1*b2v; acc[1][3]+=a1*b3v;
      acc[2][0]+=a2*b0; acc[2][1]+=a2*b1v; acc[2][2]+=a2*b2v; acc[2][3]+=a2*b3v;
      acc[3][0]+=a3*b0; acc[3][1]+=a3*b1v; acc[3][2]+=a3*b2v; acc[3][3]+=a3*b3v;
    }
    #pragma unroll
    for(int i=0;i<4;++i){
      int n=n0+4*ty+i;
      if(n<NN){
        #pragma unroll
        for(int j=0;j<4;++j){ int c=c0+4*tx+j; outp[(size_t)n*256+c]=acc[i][j]+bb[c]; }
      }
    }
  }
}

// per (edge, head): logits + atomic segment-max over tgt
__global__ __launch_bounds__(256) void k_edge_logits(const float* __restrict__ xl, const float* __restrict__ xr,
    const float* __restrict__ ea, const int* __restrict__ ei,
    const float* __restrict__ We, const float* __restrict__ att,
    float* __restrict__ elog, unsigned* __restrict__ mxu){
  __shared__ float wes[EDIM][256];
  __shared__ float atts[256];
  int tid=threadIdx.x;
  for(int idx=tid; idx<EDIM*256; idx+=256) wes[idx>>8][idx&255]=We[idx];
  atts[tid]=att[tid];
  __syncthreads();
  int g=blockIdx.x*256+tid;
  int e=g>>2, h=g&3;
  int src=ei[e], tgt=ei[NE+e];
  float ear[EDIM];
  #pragma unroll
  for(int k=0;k<EDIM;++k) ear[k]=ea[(size_t)e*EDIM+k];
  const float4* xlp=(const float4*)(xl+(size_t)src*256+h*64);
  const float4* xrp=(const float4*)(xr+(size_t)tgt*256+h*64);
  float acc=0.f;
  #pragma unroll 4
  for(int c4=0;c4<16;++c4){
    float4 xv=xlp[c4], rv=xrp[c4];
    float xa[4]={xv.x,xv.y,xv.z,xv.w}, ra[4]={rv.x,rv.y,rv.z,rv.w};
    #pragma unroll
    for(int i=0;i<4;++i){
      int c=h*64+c4*4+i;
      float ev=0.f;
      #pragma unroll
      for(int k=0;k<EDIM;++k) ev+=ear[k]*wes[k][c];
      float mm=xa[i]+ra[i]+ev;
      mm = mm>0.f?mm:0.2f*mm;
      acc += mm*atts[c];
    }
  }
  elog[g]=acc;
  atomicMax(&mxu[(size_t)tgt*4+h], ordf(acc));
}

__global__ void k_edge_exp(const int* __restrict__ ei, float* __restrict__ elog,
    const unsigned* __restrict__ mxu, float* __restrict__ den){
  int g=blockIdx.x*blockDim.x+threadIdx.x;
  int e=g>>2,h=g&3;
  int tgt=ei[NE+e];
  float m=unordf(mxu[(size_t)tgt*4+h]);
  float a=__expf(elog[g]-m);
  elog[g]=a;
  atomicAdd(&den[(size_t)tgt*4+h],a);
}

// per-node CSR gather: out[n,h,c] = sum alpha*xl[src]; mean heads + bias + layer gating
__global__ __launch_bounds__(256) void k_agg(const float* __restrict__ xl, const float* __restrict__ elog,
    const float* __restrict__ den, const int* __restrict__ ei, const int* __restrict__ row_ptr,
    const int* __restrict__ csr, const float* __restrict__ bias, const float* __restrict__ gates,
    int layer, const float* __restrict__ hprev, float* __restrict__ hout){
  __shared__ float red[4][64];
  int n=blockIdx.x, tid=threadIdx.x, h=tid>>6, c=tid&63;
  int s=row_ptr[n], t=row_ptr[n+1];
  float dn=den[(size_t)n*4+h];
  float rdn=dn>0.f?1.f/dn:0.f;
  float acc=0.f;
  for(int j=s;j<t;++j){
    int eid=csr[j];
    int srcn=ei[eid];
    float av=elog[(size_t)eid*4+h];
    acc += xl[(size_t)srcn*256+tid]*(av*rdn);
  }
  red[h][c]=acc;
  __syncthreads();
  if(tid<64){
    float mean=(red[0][tid]+red[1][tid]+red[2][tid]+red[3][tid])*0.25f + bias[tid];
    float o;
    if(layer==0) o=mean;
    else{ float g=sigm(gates[layer-1]); o=g*mean+(1.f-g)*hprev[(size_t)n*64+tid]; }
    hout[(size_t)n*64+tid]=o;
  }
}

// stable counting-sort of pairs by type; builds tile table (tiles of 64 rows, padded per group)
// meta: [0..7]=cnt [8..15]=base [16..23]=pad_base [24]=ntiles [26..161]=tile_expert [162..297]=tile_row0
__global__ __launch_bounds__(256) void k_sort(const int* __restrict__ types, int* __restrict__ meta,
    int* __restrict__ slotp, int* __restrict__ oslot, int* __restrict__ otype){
  __shared__ int cnt[256][8];
  __shared__ int tot[8];
  __shared__ int base_s[8], pad_s[8];
  int tid=threadIdx.x;
  int lc[8]={0,0,0,0,0,0,0,0};
  for(int i=0;i<32;++i){ int p=tid*32+i; lc[types[p]]++; }
  #pragma unroll
  for(int t=0;t<8;++t) cnt[tid][t]=lc[t];
  __syncthreads();
  if(tid<8){
    int run=0;
    for(int j=0;j<256;++j){ int v=cnt[j][tid]; cnt[j][tid]=run; run+=v; }
    tot[tid]=run;
  }
  __syncthreads();
  if(tid==0){
    int b=0, pb=0, nt=0;
    for(int t=0;t<8;++t){
      base_s[t]=b; pad_s[t]=pb;
      meta[t]=tot[t]; meta[8+t]=b; meta[16+t]=pb;
      int ntt=(tot[t]+TROWS-1)/TROWS;
      for(int j=0;j<ntt;++j){ meta[26+nt]=t; meta[162+nt]=pb+j*TROWS; nt++; }
      b+=tot[t]; pb+=ntt*TROWS;
    }
    meta[24]=nt;
  }
  __syncthreads();
  int run[8];
  #pragma unroll
  for(int t=0;t<8;++t) run[t]=cnt[tid][t];
  for(int i=0;i<32;++i){
    int p=tid*32+i; int t=types[p]; int r=run[t]++;
    int pos=base_s[t]+r, slot=pad_s[t]+r;
    slotp[p]=slot; oslot[pos]=slot; otype[pos]=t;
  }
}

// z0[slot, 2c]=h[a,c], z0[slot,2c+1]=h[b,c]
__global__ void k_buildz(const float* __restrict__ hfin, const int* __restrict__ ecross,
    const int* __restrict__ slotp, float* __restrict__ z){
  int g=blockIdx.x*blockDim.x+threadIdx.x;
  if(g>=NP*64) return;
  int p=g>>6, c=g&63;
  int a=ecross[2*p], b=ecross[2*p+1];
  int slot=slotp[p];
  float2 v; v.x=hfin[(size_t)a*64+c]; v.y=hfin[(size_t)b*64+c];
  ((float2*)(z+(size_t)slot*TC))[c]=v;
}

// y_partial += relu(relu(z)@W1+b1) @ W2  over this block's hid-chunk of 1024
__global__ __launch_bounds__(256) void k_resmm(const float* __restrict__ z, float* __restrict__ ybuf,
    const float* __restrict__ W1all, const float* __restrict__ b1all, const float* __restrict__ W2all,
    const int* __restrict__ meta, int rb){
  __shared__ float zr[128*ZRS];     // [k][row] transposed, relu'd
  __shared__ float wb[128*W1S];     // W1 chunk [128k][32j] OR W2 chunk [32j][128c]
  __shared__ float tst[32*TSS];     // t transposed [j][row]
  int tile=blockIdx.x;
  if(tile>=meta[24]) return;
  int e=meta[26+tile], row0=meta[162+tile];
  const float* W1 = W1all + (size_t)(e*2+rb)*TC*HIDD;
  const float* b1 = b1all + (size_t)(e*2+rb)*HIDD;
  const float* W2 = W2all + (size_t)(e*2+rb)*HIDD*TC;
  int tid=threadIdx.x, ty=tid>>4, tx=tid&15;
  for(int idx=tid; idx<TROWS*TC; idx+=256){
    int r=idx>>7, k=idx&127;
    zr[k*ZRS+r]=fmaxf(z[(size_t)(row0+r)*TC+k],0.f);
  }
  int h0=blockIdx.y*(HIDD/4);
  float yreg[4][8];
  #pragma unroll
  for(int i=0;i<4;++i){
    #pragma unroll
    for(int l=0;l<8;++l) yreg[i][l]=0.f;
  }
  for(int sub=0; sub<32; ++sub){
    int j0=h0+sub*32;
    __syncthreads();
    for(int idx=tid; idx<128*32; idx+=256){ int k=idx>>5, j=idx&31; wb[k*W1S+j]=W1[(size_t)k*HIDD + j0+j]; }
    __syncthreads();
    float b1r0=b1[j0+2*tx], b1r1=b1[j0+2*tx+1];
    float acc[4][2]={};
    #pragma unroll 8
    for(int k=0;k<128;++k){
      float4 av=*(const float4*)&zr[k*ZRS+4*ty];
      float2 wv=*(const float2*)&wb[k*W1S+2*tx];
      float a4[4]={av.x,av.y,av.z,av.w};
      #pragma unroll
      for(int i=0;i<4;++i){ acc[i][0]+=a4[i]*wv.x; acc[i][1]+=a4[i]*wv.y; }
    }
    #pragma unroll
    for(int i=0;i<4;++i){
      tst[(2*tx+0)*TSS+4*ty+i]=fmaxf(acc[i][0]+b1r0,0.f);
      tst[(2*tx+1)*TSS+4*ty+i]=fmaxf(acc[i][1]+b1r1,0.f);
    }
    __syncthreads();
    for(int idx=tid; idx<32*TC; idx+=256){ int j=idx>>7, c=idx&127; wb[j*W2S+c]=W2[(size_t)(j0+j)*TC+c]; }
    __syncthreads();
    #pragma unroll 2
    for(int j=0;j<32;++j){
      float4 tv=*(const float4*)&tst[j*TSS+4*ty];
      float4 wa=*(const float4*)&wb[j*W2S+8*tx];
      float4 wc=*(const float4*)&wb[j*W2S+8*tx+4];
      float t4[4]={tv.x,tv.y,tv.z,tv.w};
      float w8[8]={wa.x,wa.y,wa.z,wa.w,wc.x,wc.y,wc.z,wc.w};
      #pragma unroll
      for(int i=0;i<4;++i){
        #pragma unroll
        for(int l=0;l<8;++l) yreg[i][l]+=t4[i]*w8[l];
      }
    }
  }
  #pragma unroll
  for(int i=0;i<4;++i){
    int row=row0+4*ty+i;
    #pragma unroll
    for(int l=0;l<8;++l) atomicAdd(&ybuf[(size_t)row*TC+8*tx+l], yreg[i][l]);
  }
}

// zout = ge*(y+b2) + (1-ge)*relu(zin)
__global__ __launch_bounds__(256) void k_rescomb(const float* __restrict__ zin, const float* __restrict__ ybuf,
    const float* __restrict__ b2all, const float* __restrict__ gates, const int* __restrict__ meta,
    int rb, float* __restrict__ zout){
  int tile=blockIdx.x;
  if(tile>=meta[24]) return;
  int e=meta[26+tile], row0=meta[162+tile];
  float ge=sigm(gates[e*2+rb]);
  const float* b2=b2all + (size_t)(e*2+rb)*TC;
  int tid=threadIdx.x;
  for(int idx=tid; idx<TROWS*TC; idx+=256){
    int r=idx>>7, c=idx&127;
    size_t o=(size_t)(row0+r)*TC+c;
    float zrv=fmaxf(zin[o],0.f);
    zout[o]=ge*(ybuf[o]+b2[c])+(1.f-ge)*zrv;
  }
}

__global__ void k_head(const float* __restrict__ zfin, const int* __restrict__ oslot,
    const int* __restrict__ otype, const float* __restrict__ hW, const float* __restrict__ hb,
    float* __restrict__ out){
  int j=blockIdx.x*blockDim.x+threadIdx.x;
  if(j>=NP) return;
  int e=otype[j], slot=oslot[j];
  const float4* zp=(const float4*)(zfin+(size_t)slot*TC);
  const float4* wp=(const float4*)(hW+(size_t)e*TC);
  float acc=0.f;
  #pragma unroll 8
  for(int q=0;q<32;++q){
    float4 a=zp[q], b=wp[q];
    acc+=a.x*b.x+a.y*b.y+a.z*b.z+a.w*b.w;
  }
  out[j]=acc+hb[e];
}

extern "C" void kernel_launch(void* const* d_in, const int* in_sizes, int n_in,
                              void* d_out, int out_size, void* d_ws, size_t ws_size,
                              hipStream_t stream){
  const float* x     =(const float*)d_in[0];
  const int*   ei    =(const int*)  d_in[1];
  const float* ea    =(const float*)d_in[2];
  const int*   ecross=(const int*)  d_in[3];
  const int*   types =(const int*)  d_in[4];
  const float* gWl   =(const float*)d_in[5];
  const float* gbl   =(const float*)d_in[6];
  const float* gWr   =(const float*)d_in[7];
  const float* gbr   =(const float*)d_in[8];
  const float* gWe   =(const float*)d_in[9];
  const float* gatt  =(const float*)d_in[10];
  const float* gbias =(const float*)d_in[11];
  const float* ggate =(const float*)d_in[12];
  const float* rW1   =(const float*)d_in[13];
  const float* rb1   =(const float*)d_in[14];
  const float* rW2   =(const float*)d_in[15];
  const float* rb2   =(const float*)d_in[16];
  const float* rg    =(const float*)d_in[17];
  const float* hW    =(const float*)d_in[18];
  const float* hb    =(const float*)d_in[19];
  float* out=(float*)d_out;

  char* base=(char*)d_ws;
  size_t off=0;
  auto alloc=[&](size_t bytes)->char*{
    char* p=base+off;
    off=(off+bytes+511)&~((size_t)511);
    return p;
  };
  float*    xl     =(float*)   alloc((size_t)NN*256*4);
  float*    xr     =(float*)   alloc((size_t)NN*256*4);
  float*    hA     =(float*)   alloc((size_t)NN*64*4);
  float*    hB     =(float*)   alloc((size_t)NN*64*4);
  float*    elog   =(float*)   alloc((size_t)NE*4*4);
  unsigned* mxu    =(unsigned*)alloc((size_t)NN*4*4);
  float*    den    =(float*)   alloc((size_t)NN*4*4);
  int*      deg    =(int*)     alloc((size_t)NN*4);
  int*      row_ptr=(int*)     alloc((size_t)(NN+1)*4);
  int*      cursor =(int*)     alloc((size_t)NN*4);
  int*      csr    =(int*)     alloc((size_t)NE*4);
  int*      meta   =(int*)     alloc(512*4);
  int*      slotp  =(int*)     alloc((size_t)NP*4);
  int*      oslot  =(int*)     alloc((size_t)NP*4);
  int*      otype  =(int*)     alloc((size_t)NP*4);
  float*    zA     =(float*)   alloc((size_t)CAPR*TC*4);
  float*    zB     =(float*)   alloc((size_t)CAPR*TC*4);
  float*    ybuf   =(float*)   alloc((size_t)CAPR*TC*4);
  if(ws_size < off) return;   // workspace too small — bail safely

  // ---- CSR by target + pair sort (input-topology only, once) ----
  k_fill_i<<<(NN+255)/256,256,0,stream>>>(deg,NN,0);
  k_deg<<<(NE+255)/256,256,0,stream>>>(ei,deg);
  k_scan<<<1,1024,0,stream>>>(deg,row_ptr,cursor);
  k_fill_csr<<<(NE+255)/256,256,0,stream>>>(ei,cursor,csr);
  k_sort<<<1,256,0,stream>>>(types,meta,slotp,oslot,otype);

  // ---- GAT layers ----
  const float* hcur=x;
  float* hnext=hA;
  for(int L=0;L<NL;++L){
    if(L>0) k_leaky<<<(NN*64+255)/256,256,0,stream>>>((float*)hcur,NN*64);
    k_fill_i<<<(NN*4+255)/256,256,0,stream>>>((int*)mxu,NN*4,0);
    k_fill_f<<<(NN*4+255)/256,256,0,stream>>>(den,NN*4,0.f);
    k_nodexf<<<(NN+63)/64,256,0,stream>>>(hcur, gWl+(size_t)L*64*256, gbl+(size_t)L*256,
                                          gWr+(size_t)L*64*256, gbr+(size_t)L*256, xl, xr);
    k_edge_logits<<<NE*4/256,256,0,stream>>>(xl,xr,ea,ei, gWe+(size_t)L*EDIM*256, gatt+(size_t)L*256, elog, mxu);
    k_edge_exp<<<NE*4/256,256,0,stream>>>(ei,elog,mxu,den);
    k_agg<<<NN,256,0,stream>>>(xl,elog,den,ei,row_ptr,csr, gbias+(size_t)L*64, ggate, L, hcur, hnext);
    hcur=hnext;
    hnext=(hcur==hA)?hB:hA;
  }

  // ---- pair gather into type-sorted padded layout ----
  k_fill_f<<<(CAPR*TC+255)/256,256,0,stream>>>(zA,CAPR*TC,0.f);
  k_buildz<<<NP*64/256,256,0,stream>>>(hcur,ecross,slotp,zA);

  // ---- routed experts: 2 gated res-blocks ----
  float* zin=zA; float* zout=zB;
  for(int r=0;r<2;++r){
    k_fill_f<<<(CAPR*TC+255)/256,256,0,stream>>>(ybuf,CAPR*TC,0.f);
    dim3 g(MAXT,4);
    k_resmm<<<g,256,0,stream>>>(zin,ybuf,rW1,rb1,rW2,meta,r);
    k_rescomb<<<MAXT,256,0,stream>>>(zin,ybuf,rb2,rg,meta,r,zout);
    float* t=zin; zin=zout; zout=t;
  }

  // ---- head + ordered output ----
  k_head<<<NP/256,256,0,stream>>>(zin,oslot,otype,hW,hb,out);
  (void)in_sizes; (void)n_in; (void)out_size;
}

// Round 2
// 1398.920 us; speedup vs baseline: 1.5749x; 1.5749x over previous
//
#include <hip/hip_runtime.h>

#define NN 20000
#define NE 320000
#define NL 3
#define NP 8192
#define EDIM 9
#define TROWS 32
#define MAXT 272
#define CAPR (MAXT*TROWS)

typedef _Float16 f16x8 __attribute__((ext_vector_type(8)));
typedef float f32x4 __attribute__((ext_vector_type(4)));

__device__ __forceinline__ float sigm(float x){ return 1.f/(1.f+__expf(-x)); }

__global__ void k_fill_i(int* __restrict__ p, int n, int v){ int i=blockIdx.x*blockDim.x+threadIdx.x; if(i<n)p[i]=v; }

__global__ void k_leaky(float* __restrict__ h, int n){
  int i=blockIdx.x*blockDim.x+threadIdx.x;
  if(i<n){ float v=h[i]; h[i]=v>0.f?v:0.01f*v; }
}

__global__ void k_deg(const int* __restrict__ ei, int* __restrict__ deg){
  int e=blockIdx.x*blockDim.x+threadIdx.x; if(e<NE) atomicAdd(&deg[ei[NE+e]],1);
}

__global__ __launch_bounds__(1024) void k_scan(const int* __restrict__ deg, int* __restrict__ row_ptr, int* __restrict__ cursor){
  __shared__ int sh[1024];
  __shared__ int carry;
  int tid=threadIdx.x;
  if(tid==0) carry=0;
  __syncthreads();
  for(int base=0;base<NN;base+=1024){
    int i=base+tid;
    int v=(i<NN)?deg[i]:0;
    sh[tid]=v; __syncthreads();
    for(int o=1;o<1024;o<<=1){
      int t=(tid>=o)?sh[tid-o]:0; __syncthreads();
      sh[tid]+=t; __syncthreads();
    }
    int incl=sh[tid];
    int c=carry;
    if(i<NN){ row_ptr[i+1]=c+incl; cursor[i]=c+incl-v; }
    if(i==0) row_ptr[0]=0;
    __syncthreads();
    if(tid==1023) carry=c+incl;
    __syncthreads();
  }
}

__global__ void k_fill_csr(const int* __restrict__ ei, int* __restrict__ cursor, int* __restrict__ csr){
  int e=blockIdx.x*blockDim.x+threadIdx.x;
  if(e<NE){ int t=ei[NE+e]; int pos=atomicAdd(&cursor[t],1); csr[pos]=e; }
}

// stable counting-sort of pairs by type; tiles of 32 rows padded per group; islot = slot->output pos
__global__ __launch_bounds__(256) void k_sort(const int* __restrict__ types, int* __restrict__ meta,
    int* __restrict__ slotp, int* __restrict__ islot){
  __shared__ int cnt[256][8];
  __shared__ int tot[8];
  __shared__ int base_s[8], pad_s[8];
  int tid=threadIdx.x;
  int lc[8]={0,0,0,0,0,0,0,0};
  int tl[32];
  for(int i=0;i<32;++i){ int ty=types[tid*32+i]; tl[i]=ty; lc[ty]++; }
  #pragma unroll
  for(int t=0;t<8;++t) cnt[tid][t]=lc[t];
  __syncthreads();
  if(tid<8){
    int run=0;
    for(int j=0;j<256;++j){ int v=cnt[j][tid]; cnt[j][tid]=run; run+=v; }
    tot[tid]=run;
  }
  __syncthreads();
  if(tid==0){
    int b=0, pb=0, nt=0;
    for(int t=0;t<8;++t){
      base_s[t]=b; pad_s[t]=pb;
      meta[t]=tot[t]; meta[8+t]=b; meta[16+t]=pb;
      int ntt=(tot[t]+31)>>5;
      for(int j=0;j<ntt;++j){ meta[32+nt]=t; meta[32+MAXT+nt]=pb+j*32; nt++; }
      b+=tot[t]; pb+=ntt*32;
    }
    meta[24]=nt; meta[25]=pb;
  }
  __syncthreads();
  if(tid<8){
    int t=tid; int ntt=(tot[t]+31)>>5;
    for(int sr=tot[t]; sr<ntt*32; ++sr) islot[pad_s[t]+sr]=-1;
  }
  int run[8];
  #pragma unroll
  for(int t=0;t<8;++t) run[t]=cnt[tid][t];
  for(int i=0;i<32;++i){
    int p=tid*32+i; int t=tl[i]; int r=run[t]++;
    int pos=base_s[t]+r, slot=pad_s[t]+r;
    slotp[p]=slot; islot[slot]=pos;
  }
}

// xl = hin@Wl + bl ; xr = hin@Wr + br   (K=64, out 256 each)
__global__ __launch_bounds__(256) void k_nodexf(const float* __restrict__ hin,
    const float* __restrict__ Wl, const float* __restrict__ bl,
    const float* __restrict__ Wr, const float* __restrict__ br,
    float* __restrict__ xl, float* __restrict__ xr){
  __shared__ float hs[64][66];
  __shared__ float ws[64][66];
  int n0=blockIdx.x*64, tid=threadIdx.x;
  for(int idx=tid; idx<64*64; idx+=256){ int r=idx>>6,k=idx&63; int n=n0+r; hs[r][k]=(n<NN)?hin[(size_t)n*64+k]:0.f; }
  int ty=tid>>4, tx=tid&15;
  for(int ch=0; ch<8; ++ch){
    const float* W=(ch<4)?Wl:Wr;
    const float* bb=(ch<4)?bl:br;
    float* outp=(ch<4)?xl:xr;
    int c0=(ch&3)*64;
    __syncthreads();
    for(int idx=tid; idx<64*64; idx+=256){ int k=idx>>6,j=idx&63; ws[k][j]=W[(size_t)k*256+c0+j]; }
    __syncthreads();
    float acc[4][4]={};
    #pragma unroll 4
    for(int k=0;k<64;++k){
      float a0=hs[4*ty+0][k],a1=hs[4*ty+1][k],a2=hs[4*ty+2][k],a3=hs[4*ty+3][k];
      float b0=ws[k][4*tx+0],b1v=ws[k][4*tx+1],b2v=ws[k][4*tx+2],b3v=ws[k][4*tx+3];
      acc[0][0]+=a0*b0; acc[0][1]+=a0*b1v; acc[0][2]+=a0*b2v; acc[0][3]+=a0*b3v;
      acc[1][0]+=a1*b0; acc[1][1]+=a1*b1v; acc[1][2]+=a1*b2v; acc[1][3]+=a1*b3v;
      acc[2][0]+=a2*b0; acc[2][1]+=a2*b1v; acc[2][2]+=a2*b2v; acc[2][3]+=a2*b3v;
      acc[3][0]+=a3*b0; acc[3][1]+=a3*b1v; acc[3][2]+=a3*b2v; acc[3][3]+=a3*b3v;
    }
    #pragma unroll
    for(int i=0;i<4;++i){
      int n=n0+4*ty+i;
      if(n<NN){
        #pragma unroll
        for(int j=0;j<4;++j){ int c=c0+4*tx+j; outp[(size_t)n*256+c]=acc[i][j]+bb[c]; }
      }
    }
  }
}

// fused GAT edge pipeline: per target node, online logits+exp+den+aggregation (no max-sub needed)
__global__ __launch_bounds__(256) void k_agg2(const float* __restrict__ xl, const float* __restrict__ xr,
    const float* __restrict__ ea, const int* __restrict__ ei, const int* __restrict__ row_ptr,
    const int* __restrict__ csr, const float* __restrict__ WeL, const float* __restrict__ attL,
    const float* __restrict__ biasL, const float* __restrict__ gates, int layer,
    const float* __restrict__ hprev, float* __restrict__ hout){
  __shared__ float wes[9*256];
  __shared__ float red[4][64];
  int n=blockIdx.x, tid=threadIdx.x;
  for(int idx=tid; idx<9*256; idx+=256) wes[idx]=WeL[idx];
  float att_t=attL[tid];
  float xr_t=xr[(size_t)n*256+tid];
  __syncthreads();
  int s=row_ptr[n], t=row_ptr[n+1];
  float den=0.f, acc=0.f;
  for(int j=s;j<t;++j){
    int eid=csr[j];
    int srcn=ei[eid];
    const float* eap=ea+(size_t)eid*9;
    float ev=0.f;
    #pragma unroll
    for(int k=0;k<9;++k) ev+=eap[k]*wes[k*256+tid];
    float xlv=xl[(size_t)srcn*256+tid];
    float m=xlv+xr_t+ev;
    m=m>0.f?m:0.2f*m;
    float p=m*att_t;
    p+=__shfl_xor(p,1); p+=__shfl_xor(p,2); p+=__shfl_xor(p,4);
    p+=__shfl_xor(p,8); p+=__shfl_xor(p,16); p+=__shfl_xor(p,32);
    float a=__expf(p);
    den+=a; acc+=a*xlv;
  }
  float rdn=den>0.f?1.f/den:0.f;
  int h=tid>>6, cc=tid&63;
  red[h][cc]=acc*rdn;
  __syncthreads();
  if(tid<64){
    float mean=(red[0][tid]+red[1][tid]+red[2][tid]+red[3][tid])*0.25f + biasL[tid];
    float o;
    if(layer==0) o=mean;
    else{ float g=sigm(gates[layer-1]); o=g*mean+(1.f-g)*hprev[(size_t)n*64+tid]; }
    hout[(size_t)n*64+tid]=o;
  }
}

// z0[slot, 2c]=h[a,c], z0[slot,2c+1]=h[b,c]
__global__ void k_buildz(const float* __restrict__ hfin, const int* __restrict__ ecross,
    const int* __restrict__ slotp, float* __restrict__ z){
  int g=blockIdx.x*blockDim.x+threadIdx.x;
  if(g>=NP*64) return;
  int p=g>>6, c=g&63;
  int a=ecross[2*p], b=ecross[2*p+1];
  int slot=slotp[p];
  float2 v; v.x=hfin[(size_t)a*64+c]; v.y=hfin[(size_t)b*64+c];
  ((float2*)(z+(size_t)slot*128))[c]=v;
}

// generic per-slab [R][C] f32 -> [C][R] fp16 transpose (16 slabs)
__global__ __launch_bounds__(256) void k_wT(const float* __restrict__ src, _Float16* __restrict__ dst, int R, int C){
  __shared__ float lds[64][65];
  int tilesC=C>>6, per=(R>>6)*tilesC;
  int bid=blockIdx.x;
  int er=bid/per, rem=bid%per;
  int rt=rem/tilesC, ct=rem%tilesC;
  size_t slab=(size_t)er*((size_t)R*C);
  int r0=rt<<6, c0=ct<<6;
  int tid=threadIdx.x;
  #pragma unroll 4
  for(int p2=0;p2<16;++p2){
    int rr=p2*4+(tid>>6);
    lds[rr][tid&63]=src[slab+(size_t)(r0+rr)*C+c0+(tid&63)];
  }
  __syncthreads();
  #pragma unroll 4
  for(int p2=0;p2<16;++p2){
    int flat=p2*256+tid;
    int cc2=flat>>6, rr2=flat&63;
    dst[slab+(size_t)(c0+cc2)*R+r0+rr2]=(_Float16)lds[rr2][cc2];
  }
}

// fused expert res-block: zout = ge*(relu(relu(z)@W1+b1)@W2 + b2) + (1-ge)*relu(z)
// rb==1: additionally computes head dot and scatters to ordered output (zout unused)
__global__ __launch_bounds__(256) void k_expert(
    const float* __restrict__ zin, float* __restrict__ zout,
    const _Float16* __restrict__ w1t, const _Float16* __restrict__ w2t,
    const float* __restrict__ b1all, const float* __restrict__ b2all,
    const float* __restrict__ gates, const float* __restrict__ hWg,
    const float* __restrict__ hbg, const int* __restrict__ islot,
    const int* __restrict__ meta, float* __restrict__ out, int rb)
{
  __shared__ _Float16 zh[32*128];
  __shared__ _Float16 w1s[64*128];
  __shared__ _Float16 w2s[128*64];
  __shared__ _Float16 ts[32*64];
  __shared__ float red[32][2];
  int nt=meta[24];
  int v=(blockIdx.x&7)*(MAXT/8)+(blockIdx.x>>3);   // XCD-aware: one expert's tiles cluster per XCD
  if(v>=nt) return;
  int e=meta[32+v], row0=meta[32+MAXT+v];
  int er=e*2+rb;
  const _Float16* w1b=w1t+(size_t)er*524288;
  const _Float16* w2b=w2t+(size_t)er*524288;
  const float* b1g=b1all+(size_t)er*4096;
  int tid=threadIdx.x, l=tid&63, w=tid>>6;
  int s16=(w&1)*16, jh=w>>1;
  int lm=l&15, lq=l>>4;

  // stage relu(z) as fp16, XOR-swizzled
  for(int g=tid; g<512; g+=256){
    int row=g>>4, slot=g&15;
    const float* src=zin+(size_t)(row0+row)*128+slot*8;
    float4 v0=*(const float4*)src;
    float4 v1=*(const float4*)(src+4);
    f16x8 hv;
    hv[0]=(_Float16)fmaxf(v0.x,0.f); hv[1]=(_Float16)fmaxf(v0.y,0.f);
    hv[2]=(_Float16)fmaxf(v0.z,0.f); hv[3]=(_Float16)fmaxf(v0.w,0.f);
    hv[4]=(_Float16)fmaxf(v1.x,0.f); hv[5]=(_Float16)fmaxf(v1.y,0.f);
    hv[6]=(_Float16)fmaxf(v1.z,0.f); hv[7]=(_Float16)fmaxf(v1.w,0.f);
    int idx=(row*128+slot*8)^((row&7)<<3);
    *(f16x8*)(&zh[idx])=hv;
  }

  f32x4 yacc[4];
  #pragma unroll
  for(int i=0;i<4;++i){ yacc[i][0]=0.f; yacc[i][1]=0.f; yacc[i][2]=0.f; yacc[i][3]=0.f; }

  for(int c=0;c<64;++c){
    int j0=c*64;
    uint4 w1d[4], w2d[4];
    #pragma unroll
    for(int p=0;p<4;++p){
      int g=tid+p*256;
      w1d[p]=*(const uint4*)(w1b+(size_t)j0*128+g*8);
      int n=g>>3, slot=g&7;
      w2d[p]=*(const uint4*)(w2b+(size_t)n*4096+j0+slot*8);
    }
    __syncthreads();                    // prev chunk done with w1s
    #pragma unroll
    for(int p=0;p<4;++p){
      int g=tid+p*256;
      int j=g>>4;
      *(uint4*)(&w1s[(g*8)^((j&7)<<3)])=w1d[p];
    }
    __syncthreads();                    // w1s (and zh, first iter) ready
    f32x4 tacc[2];
    #pragma unroll
    for(int i=0;i<2;++i){ tacc[i][0]=0.f; tacc[i][1]=0.f; tacc[i][2]=0.f; tacc[i][3]=0.f; }
    int arow=s16+lm;
    #pragma unroll
    for(int ks=0;ks<4;++ks){
      f16x8 a=*(const f16x8*)(&zh[(arow*128+ks*32+lq*8)^((arow&7)<<3)]);
      #pragma unroll
      for(int nf=0;nf<2;++nf){
        int j=jh*32+nf*16+lm;
        f16x8 b=*(const f16x8*)(&w1s[(j*128+ks*32+lq*8)^((j&7)<<3)]);
        tacc[nf]=__builtin_amdgcn_mfma_f32_16x16x32_f16(a,b,tacc[nf],0,0,0);
      }
    }
    #pragma unroll
    for(int nf=0;nf<2;++nf){
      int j=jh*32+nf*16+lm;
      float b1v=b1g[j0+j];
      #pragma unroll
      for(int r=0;r<4;++r){
        int trow=s16+lq*4+r;
        ts[(trow*64+j)^((trow&7)<<3)]=(_Float16)fmaxf(tacc[nf][r]+b1v,0.f);
      }
    }
    #pragma unroll
    for(int p=0;p<4;++p){
      int g=tid+p*256;
      int n=g>>3;
      *(uint4*)(&w2s[(g*8)^((n&7)<<3)])=w2d[p];
    }
    __syncthreads();                    // ts + w2s ready
    #pragma unroll
    for(int ks=0;ks<2;++ks){
      f16x8 a=*(const f16x8*)(&ts[(arow*64+ks*32+lq*8)^((arow&7)<<3)]);
      #pragma unroll
      for(int nf=0;nf<4;++nf){
        int n=jh*64+nf*16+lm;
        f16x8 b=*(const f16x8*)(&w2s[(n*64+ks*32+lq*8)^((n&7)<<3)]);
        yacc[nf]=__builtin_amdgcn_mfma_f32_16x16x32_f16(a,b,yacc[nf],0,0,0);
      }
    }
  }

  float ge=sigm(gates[er]);
  const float* b2g=b2all+(size_t)er*128;
  if(rb==0){
    #pragma unroll
    for(int nf=0;nf<4;++nf){
      int col=jh*64+nf*16+lm;
      float b2v=b2g[col];
      #pragma unroll
      for(int r=0;r<4;++r){
        int row=row0+s16+lq*4+r;
        float zr=fmaxf(zin[(size_t)row*128+col],0.f);
        zout[(size_t)row*128+col]=ge*(yacc[nf][r]+b2v)+(1.f-ge)*zr;
      }
    }
  }else{
    float hbv=hbg[e];
    float psum[4]={0.f,0.f,0.f,0.f};
    #pragma unroll
    for(int nf=0;nf<4;++nf){
      int col=jh*64+nf*16+lm;
      float b2v=b2g[col];
      float hwv=hWg[e*128+col];
      #pragma unroll
      for(int r=0;r<4;++r){
        int row=row0+s16+lq*4+r;
        float zr=fmaxf(zin[(size_t)row*128+col],0.f);
        float zf=ge*(yacc[nf][r]+b2v)+(1.f-ge)*zr;
        psum[r]+=zf*hwv;
      }
    }
    #pragma unroll
    for(int r=0;r<4;++r){
      float p=psum[r];
      p+=__shfl_xor(p,1); p+=__shfl_xor(p,2); p+=__shfl_xor(p,4); p+=__shfl_xor(p,8);
      if(lm==0) red[s16+lq*4+r][jh]=p;
    }
    __syncthreads();
    if(tid<32){
      float sum=red[tid][0]+red[tid][1];
      int pos=islot[row0+tid];
      if(pos>=0) out[pos]=sum+hbv;
    }
  }
}

extern "C" void kernel_launch(void* const* d_in, const int* in_sizes, int n_in,
                              void* d_out, int out_size, void* d_ws, size_t ws_size,
                              hipStream_t stream){
  const float* x     =(const float*)d_in[0];
  const int*   ei    =(const int*)  d_in[1];
  const float* ea    =(const float*)d_in[2];
  const int*   ecross=(const int*)  d_in[3];
  const int*   types =(const int*)  d_in[4];
  const float* gWl   =(const float*)d_in[5];
  const float* gbl   =(const float*)d_in[6];
  const float* gWr   =(const float*)d_in[7];
  const float* gbr   =(const float*)d_in[8];
  const float* gWe   =(const float*)d_in[9];
  const float* gatt  =(const float*)d_in[10];
  const float* gbias =(const float*)d_in[11];
  const float* ggate =(const float*)d_in[12];
  const float* rW1   =(const float*)d_in[13];
  const float* rb1   =(const float*)d_in[14];
  const float* rW2   =(const float*)d_in[15];
  const float* rb2   =(const float*)d_in[16];
  const float* rg    =(const float*)d_in[17];
  const float* hW    =(const float*)d_in[18];
  const float* hb    =(const float*)d_in[19];
  float* out=(float*)d_out;

  char* base=(char*)d_ws;
  size_t off=0;
  auto alloc=[&](size_t bytes)->char*{
    char* p=base+off;
    off=(off+bytes+511)&~((size_t)511);
    return p;
  };
  float* hA     =(float*)alloc((size_t)NN*64*4);
  float* hB     =(float*)alloc((size_t)NN*64*4);
  int*   deg    =(int*)  alloc((size_t)NN*4);
  int*   row_ptr=(int*)  alloc((size_t)(NN+1)*4);
  int*   cursor =(int*)  alloc((size_t)NN*4);
  int*   csr    =(int*)  alloc((size_t)NE*4);
  int*   meta   =(int*)  alloc(1024*4);
  int*   slotp  =(int*)  alloc((size_t)NP*4);
  int*   islot  =(int*)  alloc((size_t)CAPR*4);
  float* zA     =(float*)alloc((size_t)CAPR*128*4);
  float* zB     =(float*)alloc((size_t)CAPR*128*4);
  // union region: {xl, xr} (GAT phase) overlaid with {w1t, w2t} (expert phase)
  size_t uoff=off;
  float* xl=(float*)(base+uoff);
  float* xr=(float*)(base+uoff+(size_t)NN*256*4);
  _Float16* w1t=(_Float16*)(base+uoff);
  _Float16* w2t=(_Float16*)(base+uoff+(size_t)16*524288*2);
  size_t gat_bytes=(size_t)NN*256*4*2;
  size_t wt_bytes=(size_t)16*524288*2*2;
  size_t need=uoff+(gat_bytes>wt_bytes?gat_bytes:wt_bytes);
  if(ws_size<need) return;

  // ---- CSR by target + pair sort (topology only) ----
  k_fill_i<<<(NN+255)/256,256,0,stream>>>(deg,NN,0);
  k_deg<<<(NE+255)/256,256,0,stream>>>(ei,deg);
  k_scan<<<1,1024,0,stream>>>(deg,row_ptr,cursor);
  k_fill_csr<<<(NE+255)/256,256,0,stream>>>(ei,cursor,csr);
  k_sort<<<1,256,0,stream>>>(types,meta,slotp,islot);

  // ---- GAT layers ----
  const float* hcur=x;
  float* hnext=hA;
  for(int L=0;L<NL;++L){
    if(L>0) k_leaky<<<(NN*64+255)/256,256,0,stream>>>((float*)hcur,NN*64);
    k_nodexf<<<(NN+63)/64,256,0,stream>>>(hcur, gWl+(size_t)L*64*256, gbl+(size_t)L*256,
                                          gWr+(size_t)L*64*256, gbr+(size_t)L*256, xl, xr);
    k_agg2<<<NN,256,0,stream>>>(xl,xr,ea,ei,row_ptr,csr, gWe+(size_t)L*EDIM*256,
                                gatt+(size_t)L*256, gbias+(size_t)L*64, ggate, L, hcur, hnext);
    hcur=hnext;
    hnext=(hcur==hA)?hB:hA;
  }

  // ---- pair gather into type-sorted padded layout ----
  k_buildz<<<NP*64/256,256,0,stream>>>(hcur,ecross,slotp,zA);

  // ---- weight transposes to fp16 (xl/xr now dead) ----
  k_wT<<<2048,256,0,stream>>>(rW1,w1t,128,4096);
  k_wT<<<2048,256,0,stream>>>(rW2,w2t,4096,128);

  // ---- routed experts: 2 fused MFMA res-blocks (second fuses head+scatter) ----
  k_expert<<<MAXT,256,0,stream>>>(zA,zB,w1t,w2t,rb1,rb2,rg,hW,hb,islot,meta,out,0);
  k_expert<<<MAXT,256,0,stream>>>(zB,zA,w1t,w2t,rb1,rb2,rg,hW,hb,islot,meta,out,1);

  (void)in_sizes; (void)n_in; (void)out_size;
}